// Round 12
// baseline (33.281 us; speedup 1.0000x reference)
//
#include <hip/hip_runtime.h>
#include <math.h>

// Dims: B=4, C=8, H=W=256
#define B_DIM 4
#define C_DIM 8
#define H_DIM 256
#define W_DIM 256
#define HW 65536
#define NPIX 262144

// ws layout (no zero-init required; every slot written every call):
// [0,     4096)   float pce[1024]
// [4096,  8192)   float pinter[1024]
// [8192, 16384)   int2  pcnt[1024]
// [16384,20480)   float pbound[1024]
// [24576,40960)   uchar rowflagP[64*256]
// [2MB,  10MB)    uint  d1t[32][16][256][16]  tiled: [bc][xt][y][word]; word = d1_pol0 | d1_pol1<<16
// [10MB, 18MB)    float probs[B][C][HW]       softmax probabilities

__device__ __forceinline__ float wave_reduce_f(float v) {
#pragma unroll
    for (int off = 32; off; off >>= 1) v += __shfl_xor(v, off, 64);
    return v;
}

// ------------- Kernel 1: fused softmax/probs + stats + horizontal EDT for one (b,y) row -----
__global__ void __launch_bounds__(256) k_row(
    const float* __restrict__ x, const int* __restrict__ tgt,
    float* __restrict__ probs, float* __restrict__ pce, float* __restrict__ pinter,
    int2* __restrict__ pcnt, unsigned char* __restrict__ rowflagP,
    unsigned int* __restrict__ d1t) {
    int bi = blockIdx.x;                 // [0,1024): b*256 + y
    int b = bi >> 8, y = bi & 255;
    int i = threadIdx.x;                 // column
    int lane = i & 63, wid = i >> 6;
    size_t rowbase = (size_t)b * HW + (size_t)y * W_DIM;

    // ---- softmax / probs / CE / Dice stats ----
    const float* xb = x + (size_t)b * C_DIM * HW + (size_t)y * W_DIM + i;
    float v[C_DIM], e[C_DIM];
    float m = -1e30f;
#pragma unroll
    for (int c = 0; c < C_DIM; ++c) { v[c] = xb[(size_t)c * HW]; m = fmaxf(m, v[c]); }
    float s = 0.f;
#pragma unroll
    for (int c = 0; c < C_DIM; ++c) { e[c] = __expf(v[c] - m); s += e[c]; }
    float rs = 1.0f / s;
    float lse = m + __logf(s);
    float* pb = probs + (size_t)b * C_DIM * HW + (size_t)y * W_DIM + i;
#pragma unroll
    for (int c = 0; c < C_DIM; ++c) pb[(size_t)c * HW] = e[c] * rs;

    int t = tgt[rowbase + i];
    bool valid_d = (t >= 0);
    bool valid_b = valid_d && (t < C_DIM);
    int tc = valid_b ? t : 0;
    float vt = v[0], et = e[0];
#pragma unroll
    for (int c = 1; c < C_DIM; ++c) { vt = (tc == c) ? v[c] : vt; et = (tc == c) ? e[c] : et; }

    float ce = lse - vt;
    float inter = valid_b ? et * rs : 0.f;

    __shared__ float ws_ce[4], ws_in[4];
    __shared__ int ws_cd[4], ws_cb[4];
    float r_ce = wave_reduce_f(ce);
    float r_in = wave_reduce_f(inter);
    unsigned long long md = __ballot(valid_d);
    unsigned long long mbv = __ballot(valid_b);
    if (lane == 0) {
        ws_ce[wid] = r_ce; ws_in[wid] = r_in;
        ws_cd[wid] = __popcll(md); ws_cb[wid] = __popcll(mbv);
    }

    // ---- row EDT via ballot masks ----
    __shared__ unsigned long long wmask[C_DIM][4];
#pragma unroll
    for (int c = 0; c < C_DIM; ++c) {
        unsigned long long mc = __ballot(valid_b && (t == c));
        if (lane == 0) wmask[c][wid] = mc;
    }
    __syncthreads();

    if (i == 0) {
        pce[bi] = (ws_ce[0] + ws_ce[1]) + (ws_ce[2] + ws_ce[3]);
        pinter[bi] = (ws_in[0] + ws_in[1]) + (ws_in[2] + ws_in[3]);
        pcnt[bi] = make_int2((ws_cd[0] + ws_cd[1]) + (ws_cd[2] + ws_cd[3]),
                             (ws_cb[0] + ws_cb[1]) + (ws_cb[2] + ws_cb[3]));
    }
    if (i < 16) {   // per-(c,pol) row seed flags
        int c = i >> 1, pol = i & 1;
        unsigned long long o = wmask[c][0] | wmask[c][1] | wmask[c][2] | wmask[c][3];
        unsigned long long a = wmask[c][0] & wmask[c][1] & wmask[c][2] & wmask[c][3];
        bool any = pol ? (a != ~0ull) : (o != 0ull);
        int j = ((b * C_DIM + c) << 1) + pol;
        rowflagP[(j << 8) + y] = any ? 1 : 0;
    }

    unsigned long long lm_le = (~0ull) >> (63 - lane);
    unsigned long long lm_ge = (~0ull) << lane;

#pragma unroll 1
    for (int c = 0; c < C_DIM; ++c) {
        unsigned long long m0 = wmask[c][wid];
        int d1v[2];
#pragma unroll
        for (int pol = 0; pol < 2; ++pol) {
            unsigned long long mk = pol ? ~m0 : m0;
            unsigned long long mle = mk & lm_le;
            unsigned long long mge = mk & lm_ge;
            int last, next;
            if (mle) last = (wid << 6) + 63 - __builtin_clzll(mle);
            else {
                last = -1000;
                for (int w = wid - 1; w >= 0; --w) {
                    unsigned long long mw = pol ? ~wmask[c][w] : wmask[c][w];
                    if (mw) { last = (w << 6) + 63 - __builtin_clzll(mw); break; }
                }
            }
            if (mge) next = (wid << 6) + __builtin_ctzll(mge);
            else {
                next = 100000;
                for (int w = wid + 1; w < 4; ++w) {
                    unsigned long long mw = pol ? ~wmask[c][w] : wmask[c][w];
                    if (mw) { next = (w << 6) + __builtin_ctzll(mw); break; }
                }
            }
            d1v[pol] = min(min(i - last, next - i), 512);
        }
        int bc = b * C_DIM + c;
        d1t[(((size_t)bc * 16 + (i >> 4)) * 256 + y) * 16 + (i & 15)] =
            (unsigned int)d1v[0] | ((unsigned int)d1v[1] << 16);
    }
}

// ------------- Kernel 2: outward-search vertical envelope (dynamic early exit) -------------
// grid 1024: blk -> bc = blk>>5, xt = (blk>>1)&15, yh = blk&1
// thread tile: 2 y-rows x 4 x-cols; one pol at a time in a single 20KB LDS plane.
#define LDS_PITCH 20
#define ENVELOPE(MA, MB)                                                        \
    {                                                                           \
        float4 qa0 = *(const float4*)&h[ybase][tx << 2];                        \
        float4 qb0 = *(const float4*)&h[ybase + 1][tx << 2];                    \
        MA.x = fminf(qa0.x, qb0.x + 1.0f); MB.x = fminf(qb0.x, qa0.x + 1.0f);   \
        MA.y = fminf(qa0.y, qb0.y + 1.0f); MB.y = fminf(qb0.y, qa0.y + 1.0f);   \
        MA.z = fminf(qa0.z, qb0.z + 1.0f); MB.z = fminf(qb0.z, qa0.z + 1.0f);   \
        MA.w = fminf(qa0.w, qb0.w + 1.0f); MB.w = fminf(qb0.w, qa0.w + 1.0f);   \
        int s = 1;                                                              \
        for (;;) {                                                              \
            int ra = max(ybase - s, 0);                                         \
            int rb = min(ybase + 1 + s, H_DIM - 1);                             \
            float4 qa = *(const float4*)&h[ra][tx << 2];                        \
            float4 qb = *(const float4*)&h[rb][tx << 2];                        \
            float s2a = (float)(s * s);                                         \
            float s2b = (float)((s + 1) * (s + 1));                             \
            MA.x = fminf(MA.x, fminf(qa.x + s2a, qb.x + s2b));                  \
            MA.y = fminf(MA.y, fminf(qa.y + s2a, qb.y + s2b));                  \
            MA.z = fminf(MA.z, fminf(qa.z + s2a, qb.z + s2b));                  \
            MA.w = fminf(MA.w, fminf(qa.w + s2a, qb.w + s2b));                  \
            MB.x = fminf(MB.x, fminf(qa.x + s2b, qb.x + s2a));                  \
            MB.y = fminf(MB.y, fminf(qa.y + s2b, qb.y + s2a));                  \
            MB.z = fminf(MB.z, fminf(qa.z + s2b, qb.z + s2a));                  \
            MB.w = fminf(MB.w, fminf(qa.w + s2b, qb.w + s2a));                  \
            float lmax = fmaxf(fmaxf(fmaxf(MA.x, MA.y), fmaxf(MA.z, MA.w)),     \
                               fmaxf(fmaxf(MB.x, MB.y), fmaxf(MB.z, MB.w)));    \
            ++s;                                                                \
            float st = (float)(s * s);                                          \
            if (s >= H_DIM || __all(st >= lmax)) break;                         \
        }                                                                       \
    }

__global__ void __launch_bounds__(256) k_cols(
    const unsigned int* __restrict__ d1t, const float* __restrict__ probs,
    const int* __restrict__ tgt,
    const unsigned char* __restrict__ rowflagP, float* __restrict__ pbound) {
    int blk = blockIdx.x;            // [0, 1024)
    int bc = blk >> 5;               // [0, 32)
    int xt = (blk >> 1) & 15;
    int yh = blk & 1;
    int b = bc >> 3, c = bc & 7;
    int tid = threadIdx.x;
    int tx = tid & 3;
    int ybase = (yh << 7) + ((tid >> 2) << 1);   // 2-row tile
    int lane = tid & 63, wid = tid >> 6;

    __shared__ float h[H_DIM][LDS_PITCH];   // one pol's squared d1 at a time
    __shared__ int anyf[2];
    __shared__ float wsum[4];

    if (tid < 2) anyf[tid] = 0;
    __syncthreads();
    {
        int j0 = bc << 1;
        unsigned char f0 = rowflagP[(j0 << 8) + tid];
        unsigned char f1 = rowflagP[((j0 + 1) << 8) + tid];
        unsigned long long b0 = __ballot(f0 != 0);
        unsigned long long b1 = __ballot(f1 != 0);
        if (lane == 0) {
            if (b0) atomicOr(&anyf[0], 1);
            if (b1) atomicOr(&anyf[1], 1);
        }
    }

    // load the packed tile into registers (16 u32/thread, coalesced 16KB)
    uint4 q[4];
    {
        const unsigned int* base = d1t + ((size_t)bc * 16 + xt) * 4096;
#pragma unroll
        for (int k = 0; k < 4; ++k)
            q[k] = *(const uint4*)(base + (k << 10) + (tid << 2));
    }

    // hoist epilogue global loads: HBM latency hides under the envelope compute
    size_t pixbase = (size_t)b * HW;
    size_t cplane = ((size_t)b * C_DIM + c) * HW;
    int x0 = (xt << 4) + (tx << 2);
    size_t row0 = (size_t)ybase * W_DIM + x0;
    size_t row1 = (size_t)(ybase + 1) * W_DIM + x0;
    float4 pv0 = *(const float4*)(probs + cplane + row0);
    float4 pv1 = *(const float4*)(probs + cplane + row1);
    int4 tv0 = *(const int4*)(tgt + pixbase + row0);
    int4 tv1 = *(const int4*)(tgt + pixbase + row1);

    int wcol = (tid & 3) << 2;

    // ---- phase A: pol0 plane ----
#pragma unroll
    for (int k = 0; k < 4; ++k) {
        int yw = (tid >> 2) + (k << 6);
        float4 f;
        f.x = (float)(q[k].x & 0xFFFFu); f.y = (float)(q[k].y & 0xFFFFu);
        f.z = (float)(q[k].z & 0xFFFFu); f.w = (float)(q[k].w & 0xFFFFu);
        f.x *= f.x; f.y *= f.y; f.z *= f.z; f.w *= f.w;
        *(float4*)&h[yw][wcol] = f;
    }
    __syncthreads();
    float4 m0a, m0b;
    ENVELOPE(m0a, m0b)
    __syncthreads();

    // ---- phase B: pol1 plane (reuse LDS) ----
#pragma unroll
    for (int k = 0; k < 4; ++k) {
        int yw = (tid >> 2) + (k << 6);
        float4 f;
        f.x = (float)(q[k].x >> 16); f.y = (float)(q[k].y >> 16);
        f.z = (float)(q[k].z >> 16); f.w = (float)(q[k].w >> 16);
        f.x *= f.x; f.y *= f.y; f.z *= f.z; f.w *= f.w;
        *(float4*)&h[yw][wcol] = f;
    }
    __syncthreads();
    float4 m1a, m1b;
    ENVELOPE(m1a, m1b)

    bool has_pos = anyf[0] != 0;
    bool has_neg = anyf[1] != 0;

    float lsum = 0.f;
#pragma unroll
    for (int iy = 0; iy < 2; ++iy) {
        float4 M0 = iy ? m0b : m0a;
        float4 M1 = iy ? m1b : m1a;
        float4 pv = iy ? pv1 : pv0;
        int4 tv = iy ? tv1 : tv0;
#pragma unroll
        for (int j = 0; j < 4; ++j) {
            float d2o = (j == 0) ? M0.x : (j == 1) ? M0.y : (j == 2) ? M0.z : M0.w;
            float d2i = (j == 0) ? M1.x : (j == 1) ? M1.y : (j == 2) ? M1.z : M1.w;
            float dout = sqrtf(d2o), din = sqrtf(d2i);
            float sgn = has_pos ? (has_neg ? (dout - din) : dout) : 0.f;
            float pr = (j == 0) ? pv.x : (j == 1) ? pv.y : (j == 2) ? pv.z : pv.w;
            int tt   = (j == 0) ? tv.x : (j == 1) ? tv.y : (j == 2) ? tv.z : tv.w;
            bool vb = (tt >= 0) && (tt < C_DIM);
            lsum += vb ? pr * sgn : 0.f;
        }
    }

    float r2 = wave_reduce_f(lsum);
    if (lane == 0) wsum[wid] = r2;
    __syncthreads();
    if (tid == 0) pbound[blk] = (wsum[0] + wsum[1]) + (wsum[2] + wsum[3]);
}

// ------------- Kernel 3: final combine (1 block) -------------
__global__ void k_finalize(const float* __restrict__ pce, const float* __restrict__ pinter,
                           const int2* __restrict__ pcnt, const float* __restrict__ pbound,
                           float* __restrict__ out) {
    int tid = threadIdx.x;
    __shared__ double dred[256];
    double s_ce = 0, s_in = 0, s_bd = 0, c_d = 0, c_b = 0;
    for (int k = tid; k < 1024; k += 256) {
        s_ce += (double)pce[k]; s_in += (double)pinter[k];
        int2 cc = pcnt[k]; c_d += (double)cc.x; c_b += (double)cc.y;
        s_bd += (double)pbound[k];
    }

    double sums[4]; double vin[4] = {s_ce, s_in, s_bd, c_d * 4194304.0 + c_b};
    for (int q = 0; q < 4; ++q) {
        dred[tid] = vin[q];
        __syncthreads();
        for (int s2 = 128; s2; s2 >>= 1) { if (tid < s2) dred[tid] += dred[tid + s2]; __syncthreads(); }
        sums[q] = dred[0];
        __syncthreads();
    }
    if (tid == 0) {
        double packed = sums[3];
        double cd = floor(packed / 4194304.0 + 1e-9);
        double cb = packed - cd * 4194304.0;
        double ce = sums[0] / (double)NPIX;
        double inter = sums[1];
        double card = cd + cb;
        double dice = 1.0 - (2.0 * inter + 1e-6) / (card + 1e-6);
        double dice_total = 0.1 * ce + 0.9 * dice;
        double bound = sums[2] / (cb + 1e-8);
        out[0] = (float)(0.1 * ce + 0.8 * dice_total + 0.1 * bound);
    }
}

extern "C" void kernel_launch(void* const* d_in, const int* in_sizes, int n_in,
                              void* d_out, int out_size, void* d_ws, size_t ws_size,
                              hipStream_t stream) {
    const float* x = (const float*)d_in[0];
    const int* tgt = (const int*)d_in[1];
    float* out = (float*)d_out;

    char* ws = (char*)d_ws;
    float* pce    = (float*)(ws + 0);
    float* pinter = (float*)(ws + 4096);
    int2*  pcnt   = (int2*)(ws + 8192);
    float* pbound = (float*)(ws + 16384);
    unsigned char* rowflagP = (unsigned char*)(ws + 24576);
    unsigned int* d1t = (unsigned int*)(ws + (size_t)(2u << 20));
    float* probs  = (float*)(ws + (size_t)(10u << 20));

    k_row<<<1024, 256, 0, stream>>>(x, tgt, probs, pce, pinter, pcnt, rowflagP, d1t);
    k_cols<<<1024, 256, 0, stream>>>(d1t, probs, tgt, rowflagP, pbound);
    k_finalize<<<1, 256, 0, stream>>>(pce, pinter, pcnt, pbound, out);
}

// Round 13
// 27.730 us; speedup vs baseline: 1.2002x; 1.2002x over previous
//
#include <hip/hip_runtime.h>
#include <math.h>

// Dims: B=4, C=8, H=W=256
#define B_DIM 4
#define C_DIM 8
#define H_DIM 256
#define W_DIM 256
#define HW 65536
#define NPIX 262144

// ws layout (no zero-init required; every slot written every call):
// [0,     4096)   float pce[1024]
// [4096,  8192)   float pinter[1024]
// [8192, 16384)   int2  pcnt[1024]
// [16384,20480)   float pbound[1024]
// [65536,+1MB)    float lse[NPIX]
// [2MB, +256KB)   u64   wmask_g[32][256][4]   row seed bitmasks per (bc, y); bit g of word w = col w*64+g

__device__ __forceinline__ float wave_reduce_f(float v) {
#pragma unroll
    for (int off = 32; off; off >>= 1) v += __shfl_xor(v, off, 64);
    return v;
}

// ------------- Kernel 1: fused softmax stats + row seed-mask generation -------------
__global__ void __launch_bounds__(256) k_row(
    const float* __restrict__ x, const int* __restrict__ tgt,
    float* __restrict__ lse_out, float* __restrict__ pce, float* __restrict__ pinter,
    int2* __restrict__ pcnt, unsigned long long* __restrict__ wmask_g) {
    int bi = blockIdx.x;                 // [0,1024): b*256 + y
    int b = bi >> 8, y = bi & 255;
    int i = threadIdx.x;                 // column
    int lane = i & 63, wid = i >> 6;
    size_t rowbase = (size_t)b * HW + (size_t)y * W_DIM;

    // ---- softmax / CE / Dice stats ----
    const float* xb = x + (size_t)b * C_DIM * HW + (size_t)y * W_DIM + i;
    float v[C_DIM];
    float m = -1e30f;
#pragma unroll
    for (int c = 0; c < C_DIM; ++c) { v[c] = xb[(size_t)c * HW]; m = fmaxf(m, v[c]); }
    float s = 0.f;
#pragma unroll
    for (int c = 0; c < C_DIM; ++c) s += __expf(v[c] - m);
    float lse = m + __logf(s);
    lse_out[rowbase + i] = lse;

    int t = tgt[rowbase + i];
    bool valid_d = (t >= 0);
    bool valid_b = valid_d && (t < C_DIM);
    int tc = valid_b ? t : 0;
    float vt = v[0];
#pragma unroll
    for (int c = 1; c < C_DIM; ++c) vt = (tc == c) ? v[c] : vt;

    float ce = lse - vt;
    float inter = valid_b ? __expf(vt - lse) : 0.f;

    __shared__ float ws_ce[4], ws_in[4];
    __shared__ int ws_cd[4], ws_cb[4];
    float r_ce = wave_reduce_f(ce);
    float r_in = wave_reduce_f(inter);
    unsigned long long md = __ballot(valid_d);
    unsigned long long mbv = __ballot(valid_b);
    if (lane == 0) {
        ws_ce[wid] = r_ce; ws_in[wid] = r_in;
        ws_cd[wid] = __popcll(md); ws_cb[wid] = __popcll(mbv);
    }

    // ---- row seed bitmasks ----
    __shared__ unsigned long long wmask[C_DIM][4];
#pragma unroll
    for (int c = 0; c < C_DIM; ++c) {
        unsigned long long mc = __ballot(valid_b && (t == c));
        if (lane == 0) wmask[c][wid] = mc;
    }
    __syncthreads();

    if (i == 0) {
        pce[bi] = (ws_ce[0] + ws_ce[1]) + (ws_ce[2] + ws_ce[3]);
        pinter[bi] = (ws_in[0] + ws_in[1]) + (ws_in[2] + ws_in[3]);
        pcnt[bi] = make_int2((ws_cd[0] + ws_cd[1]) + (ws_cd[2] + ws_cd[3]),
                             (ws_cb[0] + ws_cb[1]) + (ws_cb[2] + ws_cb[3]));
    }
    if (i < 32) {   // store masks: [bc][y][w]
        int c = i >> 2, w = i & 3;
        wmask_g[((size_t)((b * C_DIM + c) * 256 + y) << 2) + w] = wmask[c][w];
    }
}

// ------------- Kernel 2: mask->d1 reconstruction + outward envelope + boundary sum ---------
// grid 1024: blk -> bc = blk>>5, xt = (blk>>1)&15, yh = blk&1
// staging: thread tid owns row y=tid, computes d1^2 for the block's 16 cols from bitmasks.
// envelope thread tile: 2 y-rows x 4 x-cols; one pol at a time in a 20KB LDS plane.
#define LDS_PITCH 20
#define ENVELOPE(MA, MB)                                                        \
    {                                                                           \
        float4 qa0 = *(const float4*)&h[ybase][tx << 2];                        \
        float4 qb0 = *(const float4*)&h[ybase + 1][tx << 2];                    \
        MA.x = fminf(qa0.x, qb0.x + 1.0f); MB.x = fminf(qb0.x, qa0.x + 1.0f);   \
        MA.y = fminf(qa0.y, qb0.y + 1.0f); MB.y = fminf(qb0.y, qa0.y + 1.0f);   \
        MA.z = fminf(qa0.z, qb0.z + 1.0f); MB.z = fminf(qb0.z, qa0.z + 1.0f);   \
        MA.w = fminf(qa0.w, qb0.w + 1.0f); MB.w = fminf(qb0.w, qa0.w + 1.0f);   \
        int s = 1;                                                              \
        for (;;) {                                                              \
            int ra = max(ybase - s, 0);                                         \
            int rb = min(ybase + 1 + s, H_DIM - 1);                             \
            float4 qa = *(const float4*)&h[ra][tx << 2];                        \
            float4 qb = *(const float4*)&h[rb][tx << 2];                        \
            float s2a = (float)(s * s);                                         \
            float s2b = (float)((s + 1) * (s + 1));                             \
            MA.x = fminf(MA.x, fminf(qa.x + s2a, qb.x + s2b));                  \
            MA.y = fminf(MA.y, fminf(qa.y + s2a, qb.y + s2b));                  \
            MA.z = fminf(MA.z, fminf(qa.z + s2a, qb.z + s2b));                  \
            MA.w = fminf(MA.w, fminf(qa.w + s2a, qb.w + s2b));                  \
            MB.x = fminf(MB.x, fminf(qa.x + s2b, qb.x + s2a));                  \
            MB.y = fminf(MB.y, fminf(qa.y + s2b, qb.y + s2a));                  \
            MB.z = fminf(MB.z, fminf(qa.z + s2b, qb.z + s2a));                  \
            MB.w = fminf(MB.w, fminf(qa.w + s2b, qb.w + s2a));                  \
            float lmax = fmaxf(fmaxf(fmaxf(MA.x, MA.y), fmaxf(MA.z, MA.w)),     \
                               fmaxf(fmaxf(MB.x, MB.y), fmaxf(MB.z, MB.w)));    \
            ++s;                                                                \
            float st = (float)(s * s);                                          \
            if (s >= H_DIM || __all(st >= lmax)) break;                         \
        }                                                                       \
    }

__global__ void __launch_bounds__(256) k_cols(
    const unsigned long long* __restrict__ wmask_g, const float* __restrict__ x,
    const float* __restrict__ lse, const int* __restrict__ tgt,
    float* __restrict__ pbound) {
    int blk = blockIdx.x;            // [0, 1024)
    int bc = blk >> 5;               // [0, 32)
    int xt = (blk >> 1) & 15;
    int yh = blk & 1;
    int b = bc >> 3, c = bc & 7;
    int tid = threadIdx.x;
    int tx = tid & 3;
    int ybase = (yh << 7) + ((tid >> 2) << 1);   // 2-row tile
    int lane = tid & 63, wid = tid >> 6;

    __shared__ float h[H_DIM][LDS_PITCH];
    __shared__ int anyf[2];
    __shared__ float wsum[4];

    // hoist epilogue global loads: latency hides under mask->d1 compute + envelope
    size_t pixbase = (size_t)b * HW;
    size_t xplane = ((size_t)b * C_DIM + c) * HW;
    int x0 = (xt << 4) + (tx << 2);
    size_t row0 = (size_t)ybase * W_DIM + x0;
    size_t row1 = row0 + W_DIM;
    float4 xv0 = *(const float4*)(x + xplane + row0);
    float4 xv1 = *(const float4*)(x + xplane + row1);
    float4 lv0 = *(const float4*)(lse + pixbase + row0);
    float4 lv1 = *(const float4*)(lse + pixbase + row1);
    int4 tv0 = *(const int4*)(tgt + pixbase + row0);
    int4 tv1 = *(const int4*)(tgt + pixbase + row1);

    // load this row's masks (row = tid)
    const unsigned long long* mrow = wmask_g + ((size_t)(bc * 256 + tid) << 2);
    unsigned long long w0 = mrow[0], w1 = mrow[1], w2 = mrow[2], w3 = mrow[3];

    if (tid < 2) anyf[tid] = 0;
    __syncthreads();
    {
        unsigned long long orv = w0 | w1 | w2 | w3;
        unsigned long long andv = w0 & w1 & w2 & w3;
        unsigned long long bp = __ballot(orv != 0ull);
        unsigned long long bn = __ballot(andv != ~0ull);
        if (lane == 0) {
            if (bp) atomicOr(&anyf[0], 1);
            if (bn) atomicOr(&anyf[1], 1);
        }
    }

    // ---- reconstruct d1^2 for this row's 16 cols, both pols (branch-free selects) ----
    int wi = xt >> 2;            // word containing all 16 cols (block-uniform)
    int b0base = (xt & 3) << 4;  // bit offset of col 0 within that word
    int gc0 = xt << 4;           // global col of i2=0
    int wbase = wi << 6;

    float d1sq0[16], d1sq1[16];
#pragma unroll
    for (int pol = 0; pol < 2; ++pol) {
        unsigned long long q0 = pol ? ~w0 : w0;
        unsigned long long q1 = pol ? ~w1 : w1;
        unsigned long long q2 = pol ? ~w2 : w2;
        unsigned long long q3 = pol ? ~w3 : w3;
        // prefix: highest set-bit global position among words 0..k
        int h0p = q0 ? (63 - __builtin_clzll(q0)) : -100000;
        int h1p = q1 ? (127 - __builtin_clzll(q1)) : h0p;
        int h2p = q2 ? (191 - __builtin_clzll(q2)) : h1p;
        int lastp = (wi == 0) ? -100000 : (wi == 1) ? h0p : (wi == 2) ? h1p : h2p;
        // suffix: lowest set-bit global position among words k..3
        int l3p = q3 ? (192 + __builtin_ctzll(q3)) : 100000;
        int l2p = q2 ? (128 + __builtin_ctzll(q2)) : l3p;
        int l1p = q1 ? (64 + __builtin_ctzll(q1)) : l2p;
        int nextp = (wi == 0) ? l1p : (wi == 1) ? l2p : (wi == 2) ? l3p : 100000;
        unsigned long long wn = (wi == 0) ? q0 : (wi == 1) ? q1 : (wi == 2) ? q2 : q3;
#pragma unroll
        for (int i2 = 0; i2 < 16; ++i2) {
            int b0 = b0base + i2;
            unsigned long long mle = wn & ((~0ull) >> (63 - b0));
            unsigned long long mge = wn & ((~0ull) << b0);
            int last = mle ? (wbase + 63 - __builtin_clzll(mle)) : lastp;
            int next = mge ? (wbase + __builtin_ctzll(mge)) : nextp;
            int gcol = gc0 + i2;
            int d1 = min(min(gcol - last, next - gcol), 512);
            float fd = (float)(d1 * d1);
            if (pol == 0) d1sq0[i2] = fd; else d1sq1[i2] = fd;
        }
    }

    // ---- phase A: pol0 plane ----
    *(float4*)&h[tid][0]  = make_float4(d1sq0[0], d1sq0[1], d1sq0[2], d1sq0[3]);
    *(float4*)&h[tid][4]  = make_float4(d1sq0[4], d1sq0[5], d1sq0[6], d1sq0[7]);
    *(float4*)&h[tid][8]  = make_float4(d1sq0[8], d1sq0[9], d1sq0[10], d1sq0[11]);
    *(float4*)&h[tid][12] = make_float4(d1sq0[12], d1sq0[13], d1sq0[14], d1sq0[15]);
    __syncthreads();
    float4 m0a, m0b;
    ENVELOPE(m0a, m0b)
    __syncthreads();

    // ---- phase B: pol1 plane (reuse LDS) ----
    *(float4*)&h[tid][0]  = make_float4(d1sq1[0], d1sq1[1], d1sq1[2], d1sq1[3]);
    *(float4*)&h[tid][4]  = make_float4(d1sq1[4], d1sq1[5], d1sq1[6], d1sq1[7]);
    *(float4*)&h[tid][8]  = make_float4(d1sq1[8], d1sq1[9], d1sq1[10], d1sq1[11]);
    *(float4*)&h[tid][12] = make_float4(d1sq1[12], d1sq1[13], d1sq1[14], d1sq1[15]);
    __syncthreads();
    float4 m1a, m1b;
    ENVELOPE(m1a, m1b)

    bool has_pos = anyf[0] != 0;
    bool has_neg = anyf[1] != 0;

    float lsum = 0.f;
#pragma unroll
    for (int iy = 0; iy < 2; ++iy) {
        float4 M0 = iy ? m0b : m0a;
        float4 M1 = iy ? m1b : m1a;
        float4 xv = iy ? xv1 : xv0;
        float4 lv = iy ? lv1 : lv0;
        int4 tv = iy ? tv1 : tv0;
#pragma unroll
        for (int j = 0; j < 4; ++j) {
            float d2o = (j == 0) ? M0.x : (j == 1) ? M0.y : (j == 2) ? M0.z : M0.w;
            float d2i = (j == 0) ? M1.x : (j == 1) ? M1.y : (j == 2) ? M1.z : M1.w;
            float dout = sqrtf(d2o), din = sqrtf(d2i);
            float sgn = has_pos ? (has_neg ? (dout - din) : dout) : 0.f;
            float xs = (j == 0) ? xv.x : (j == 1) ? xv.y : (j == 2) ? xv.z : xv.w;
            float ls = (j == 0) ? lv.x : (j == 1) ? lv.y : (j == 2) ? lv.z : lv.w;
            int tt   = (j == 0) ? tv.x : (j == 1) ? tv.y : (j == 2) ? tv.z : tv.w;
            bool vb = (tt >= 0) && (tt < C_DIM);
            float prob = __expf(xs - ls);
            lsum += vb ? prob * sgn : 0.f;
        }
    }

    float r2 = wave_reduce_f(lsum);
    if (lane == 0) wsum[wid] = r2;
    __syncthreads();
    if (tid == 0) pbound[blk] = (wsum[0] + wsum[1]) + (wsum[2] + wsum[3]);
}

// ------------- Kernel 3: final combine (1 block) -------------
__global__ void k_finalize(const float* __restrict__ pce, const float* __restrict__ pinter,
                           const int2* __restrict__ pcnt, const float* __restrict__ pbound,
                           float* __restrict__ out) {
    int tid = threadIdx.x;
    __shared__ double dred[256];
    double s_ce = 0, s_in = 0, s_bd = 0, c_d = 0, c_b = 0;
    for (int k = tid; k < 1024; k += 256) {
        s_ce += (double)pce[k]; s_in += (double)pinter[k];
        int2 cc = pcnt[k]; c_d += (double)cc.x; c_b += (double)cc.y;
        s_bd += (double)pbound[k];
    }

    double sums[4]; double vin[4] = {s_ce, s_in, s_bd, c_d * 4194304.0 + c_b};
    for (int q = 0; q < 4; ++q) {
        dred[tid] = vin[q];
        __syncthreads();
        for (int s2 = 128; s2; s2 >>= 1) { if (tid < s2) dred[tid] += dred[tid + s2]; __syncthreads(); }
        sums[q] = dred[0];
        __syncthreads();
    }
    if (tid == 0) {
        double packed = sums[3];
        double cd = floor(packed / 4194304.0 + 1e-9);
        double cb = packed - cd * 4194304.0;
        double ce = sums[0] / (double)NPIX;
        double inter = sums[1];
        double card = cd + cb;
        double dice = 1.0 - (2.0 * inter + 1e-6) / (card + 1e-6);
        double dice_total = 0.1 * ce + 0.9 * dice;
        double bound = sums[2] / (cb + 1e-8);
        out[0] = (float)(0.1 * ce + 0.8 * dice_total + 0.1 * bound);
    }
}

extern "C" void kernel_launch(void* const* d_in, const int* in_sizes, int n_in,
                              void* d_out, int out_size, void* d_ws, size_t ws_size,
                              hipStream_t stream) {
    const float* x = (const float*)d_in[0];
    const int* tgt = (const int*)d_in[1];
    float* out = (float*)d_out;

    char* ws = (char*)d_ws;
    float* pce    = (float*)(ws + 0);
    float* pinter = (float*)(ws + 4096);
    int2*  pcnt   = (int2*)(ws + 8192);
    float* pbound = (float*)(ws + 16384);
    float* lse    = (float*)(ws + 65536);
    unsigned long long* wmask_g = (unsigned long long*)(ws + (size_t)(2u << 20));

    k_row<<<1024, 256, 0, stream>>>(x, tgt, lse, pce, pinter, pcnt, wmask_g);
    k_cols<<<1024, 256, 0, stream>>>(wmask_g, x, lse, tgt, pbound);
    k_finalize<<<1, 256, 0, stream>>>(pce, pinter, pcnt, pbound, out);
}